// Round 1
// baseline (8829.988 us; speedup 1.0000x reference)
//
#include <hip/hip_runtime.h>
#include <hip/hip_bf16.h>
#include <math.h>

// Decoder_60112362275053: VRNN decoder. B=1024 T=256 Z=32 H=256 D=256 X=64.
// Key insight: recurrence is row-local in batch -> persistent kernel, each
// block owns RR=4 batch rows, loops t=0..255 with NO inter-block sync.
// Weights converted to bf16 + transposed once per launch into d_ws so the
// inner k-loops do coalesced 64x-consecutive-ushort reads (128B/wave).

#define TT 256
#define ZZ 32
#define HH 256
#define DD 256
#define XX 64
#define RR 4
#define BTX 16777216u  // 1024*256*64

// ws layout (bf16/ushort elements):
//   WihT  [32][768]  @ 0        (24576)
//   WhhT  [256][768] @ 24576    (196608)
//   WphiT [256][256] @ 221184   (65536)
//   WmT   [256][64]  @ 286720   (16384)
//   WsT   [256][64]  @ 303104   (16384)   total 319488 elems = 639KB

__device__ __forceinline__ float bf2f(ushort u) {
  union { unsigned int i; float f; } v; v.i = ((unsigned int)u) << 16; return v.f;
}
__device__ __forceinline__ float sigm(float x) { return 1.f / (1.f + __expf(-x)); }
__device__ __forceinline__ float tanh_f(float x) { return 2.f / (1.f + __expf(-2.f * x)) - 1.f; }
__device__ __forceinline__ float softplus_f(float x) {
  return fmaxf(x, 0.f) + log1pf(__expf(-fabsf(x)));
}

extern "C" __global__ void vrnn_prep(const float* __restrict__ Wih, const float* __restrict__ Whh,
                                     const float* __restrict__ Wphi, const float* __restrict__ Wm,
                                     const float* __restrict__ Ws, ushort* __restrict__ o)
{
  int i = blockIdx.x * 256 + threadIdx.x;
  float v;
  if (i < 24576) {                       // WihT[k][j] = Wih[j][k]
    int k = i / 768, j = i - k * 768; v = Wih[j * ZZ + k];
  } else if (i < 221184) {               // WhhT
    int q = i - 24576; int k = q / 768, j = q - k * 768; v = Whh[j * HH + k];
  } else if (i < 286720) {               // WphiT
    int q = i - 221184; int k = q >> 8, j = q & 255; v = Wphi[j * HH + k];
  } else if (i < 303104) {               // WmT
    int q = i - 286720; int k = q >> 6, j = q & 63; v = Wm[j * DD + k];
  } else if (i < 319488) {               // WsT
    int q = i - 303104; int k = q >> 6, j = q & 63; v = Ws[j * DD + k];
  } else return;
  __hip_bfloat16 b = __float2bfloat16(v);
  union { __hip_bfloat16 h; ushort u; } cv; cv.h = b;
  o[i] = cv.u;
}

extern "C" __global__ void __launch_bounds__(256)
vrnn_main(const float* __restrict__ inp, const float* __restrict__ eps,
          const float* __restrict__ b_ih, const float* __restrict__ b_hh,
          const float* __restrict__ b_phi, const float* __restrict__ b_mean,
          const float* __restrict__ b_std,
          const ushort* __restrict__ wt, float* __restrict__ out)
{
  __shared__ float h_lds[2][RR][HH];   // double-buffered hidden state
  __shared__ float x_lds[RR][ZZ];
  __shared__ float phi_lds[RR][DD];
  __shared__ float ms_lds[2][RR][XX];  // [0]=mean [1]=std

  const int t  = threadIdx.x;          // 0..255
  const int b0 = blockIdx.x * RR;      // first batch row of this block

  const ushort* WihT  = wt;
  const ushort* WhhT  = wt + 24576;
  const ushort* WphiT = wt + 221184;
  const ushort* WmT   = wt + 286720;
  const ushort* WsT   = wt + 303104;

  #pragma unroll
  for (int r = 0; r < RR; ++r) h_lds[0][r][t] = 0.f;

  // per-thread constants (t indexes gate/phi column)
  const float bias_r  = b_ih[t]       + b_hh[t];
  const float bias_z  = b_ih[t + 256] + b_hh[t + 256];
  const float bias_in = b_ih[t + 512];           // r multiplies only the hh part
  const float bias_hn = b_hh[t + 512];
  const float bias_p  = b_phi[t];
  // phase-3 mapping: 256 threads = 64 cols x {mean,std} x 2 row-pairs
  const int   c3  = t & 63;
  const int   r3  = (t >> 6) & 1;
  const int   sel = (t >> 7) & 1;
  const float bias_ms = sel ? b_std[c3] : b_mean[c3];
  const ushort* Wms   = sel ? WsT : WmT;

  int cur = 0;
  for (int step = 0; step < TT; ++step) {
    // ---- stage x_t for this block's rows ----
    if (t < RR * ZZ) {
      int r = t >> 5, k = t & 31;
      x_lds[r][k] = inp[((size_t)(b0 + r) * TT + step) * ZZ + k];
    }
    __syncthreads();

    // ---- phase 1: gi + gh + gates -> h_new (thread t owns gate col t) ----
    float a_r[RR], a_z[RR], a_in[RR], a_hn[RR];
    #pragma unroll
    for (int r = 0; r < RR; ++r) { a_r[r] = bias_r; a_z[r] = bias_z; a_in[r] = bias_in; a_hn[r] = bias_hn; }

    #pragma unroll 4
    for (int k = 0; k < ZZ; ++k) {
      float wr = bf2f(WihT[k * 768 + t]);
      float wz = bf2f(WihT[k * 768 + t + 256]);
      float wn = bf2f(WihT[k * 768 + t + 512]);
      #pragma unroll
      for (int r = 0; r < RR; ++r) {
        float xv = x_lds[r][k];
        a_r[r]  = fmaf(xv, wr, a_r[r]);
        a_z[r]  = fmaf(xv, wz, a_z[r]);
        a_in[r] = fmaf(xv, wn, a_in[r]);
      }
    }
    #pragma unroll 4
    for (int k = 0; k < HH; ++k) {
      float wr = bf2f(WhhT[k * 768 + t]);
      float wz = bf2f(WhhT[k * 768 + t + 256]);
      float wn = bf2f(WhhT[k * 768 + t + 512]);
      #pragma unroll
      for (int r = 0; r < RR; ++r) {
        float hv = h_lds[cur][r][k];        // wave-uniform address -> LDS broadcast
        a_r[r]  = fmaf(hv, wr, a_r[r]);
        a_z[r]  = fmaf(hv, wz, a_z[r]);
        a_hn[r] = fmaf(hv, wn, a_hn[r]);
      }
    }
    #pragma unroll
    for (int r = 0; r < RR; ++r) {
      float rg = sigm(a_r[r]);
      float zg = sigm(a_z[r]);
      float ng = tanh_f(fmaf(rg, a_hn[r], a_in[r]));
      h_lds[cur ^ 1][r][t] = (1.f - zg) * ng + zg * h_lds[cur][r][t];
    }
    __syncthreads();

    // ---- phase 2: phi = relu(h_new @ WphiT + b) (thread t owns phi col t) ----
    float p[RR];
    #pragma unroll
    for (int r = 0; r < RR; ++r) p[r] = bias_p;
    #pragma unroll 4
    for (int k = 0; k < HH; ++k) {
      float w = bf2f(WphiT[k * DD + t]);
      #pragma unroll
      for (int r = 0; r < RR; ++r)
        p[r] = fmaf(h_lds[cur ^ 1][r][k], w, p[r]);
    }
    #pragma unroll
    for (int r = 0; r < RR; ++r) phi_lds[r][t] = fmaxf(p[r], 0.f);
    __syncthreads();

    // ---- phase 3: mean/std (each thread: 2 rows of one output col) ----
    float m0 = bias_ms, m1 = bias_ms;
    #pragma unroll 4
    for (int k = 0; k < DD; ++k) {
      float w = bf2f(Wms[k * XX + c3]);
      m0 = fmaf(phi_lds[r3][k],     w, m0);
      m1 = fmaf(phi_lds[r3 + 2][k], w, m1);
    }
    if (sel) { ms_lds[1][r3][c3] = softplus_f(m0); ms_lds[1][r3 + 2][c3] = softplus_f(m1); }
    else     { ms_lds[0][r3][c3] = sigm(m0);       ms_lds[0][r3 + 2][c3] = sigm(m1); }
    __syncthreads();

    // ---- write xs / means / stds ----
    {
      int r = t >> 6, c = t & 63;
      size_t o = ((size_t)(b0 + r) * TT + step) * XX + c;
      float mn = ms_lds[0][r][c], sd = ms_lds[1][r][c];
      out[o]               = fmaf(eps[o], sd, mn);
      out[o + BTX]         = mn;
      out[o + 2u * BTX]    = sd;
    }
    __syncthreads();
    cur ^= 1;
  }
}

extern "C" void kernel_launch(void* const* d_in, const int* in_sizes, int n_in,
                              void* d_out, int out_size, void* d_ws, size_t ws_size,
                              hipStream_t stream)
{
  const float* inp    = (const float*)d_in[0];
  const float* eps    = (const float*)d_in[1];
  const float* W_ih   = (const float*)d_in[2];
  const float* W_hh   = (const float*)d_in[3];
  const float* b_ih   = (const float*)d_in[4];
  const float* b_hh   = (const float*)d_in[5];
  const float* W_phi  = (const float*)d_in[6];
  const float* b_phi  = (const float*)d_in[7];
  const float* W_mean = (const float*)d_in[8];
  const float* b_mean = (const float*)d_in[9];
  const float* W_std  = (const float*)d_in[10];
  const float* b_std  = (const float*)d_in[11];
  ushort* wt = (ushort*)d_ws;          // 639KB of bf16 transposed weights
  float* out = (float*)d_out;

  vrnn_prep<<<1248, 256, 0, stream>>>(W_ih, W_hh, W_phi, W_mean, W_std, wt);
  vrnn_main<<<256, 256, 0, stream>>>(inp, eps, b_ih, b_hh, b_phi, b_mean, b_std, wt, out);
}

// Round 3
// 3345.384 us; speedup vs baseline: 2.6395x; 2.6395x over previous
//
#include <hip/hip_runtime.h>
#include <hip/hip_bf16.h>
#include <math.h>

// Decoder_60112362275053: VRNN decoder. B=1024 T=256 Z=32 H=256 D=256 X=64.
// Round 2 (resubmit; round-2 bench was an infra timeout): MFMA rewrite.
// 64 blocks x 512 threads (8 waves); each block owns 16 batch rows for the
// whole T-loop. Weights pre-packed into bf16 MFMA B-fragment order
// (1KB/fragment, one dwordx4 per lane from L2). h/phi/x staged in LDS with
// padded strides (2-way bank aliasing = free). 4 barriers/step.
//
// Fragment conventions (mfma_f32_16x16x32_bf16):
//   A: lane l -> row = l&15, k = kb*32 + 8*(l>>4) + j   (j=0..7, one b128 read)
//   B: lane l -> col = l&15, k = kb*32 + 8*(l>>4) + j   (pre-packed, same map;
//      any k-permutation mismatch vs HW cancels because A and B use the same map)
//   C/D: lane l, reg q -> col = l&15, row = (l>>4)*4 + q   [HW-verified m89/m91]

typedef __attribute__((ext_vector_type(8))) short bf16x8;
typedef __attribute__((ext_vector_type(4))) float f32x4;

#define MFMA(a, b, c) __builtin_amdgcn_mfma_f32_16x16x32_bf16((a), (b), (c), 0, 0, 0)
#define LDFRAG(p) (*reinterpret_cast<const bf16x8*>(p))

// packed ws layout (ushort offsets), fragment = 512 ushorts (64 lanes x 8):
//   pWhh  @ 0      : 48 col-tiles x 8 kb   (768x256)
//   pWih  @ 196608 : 48 col-tiles x 1 kb   (768x32)
//   pWphi @ 221184 : 16 col-tiles x 8 kb   (256x256)
//   pWms  @ 286720 :  8 col-tiles x 8 kb   (128x256, cols 0-63 mean | 64-127 std)
#define OFF_WIH  196608
#define OFF_WPHI 221184
#define OFF_WMS  286720
#define N_PACK_THREADS 39936

__device__ __forceinline__ float bf2f(ushort u) {
  union { unsigned int i; float f; } v; v.i = ((unsigned int)u) << 16; return v.f;
}
__device__ __forceinline__ ushort f2bf(float f) {
  union { __hip_bfloat16 h; ushort u; } cv; cv.h = __float2bfloat16(f); return cv.u;
}
__device__ __forceinline__ float sigm(float x) { return 1.f / (1.f + __expf(-x)); }
__device__ __forceinline__ float tanh_f(float x) { return 2.f / (1.f + __expf(-2.f * x)) - 1.f; }
__device__ __forceinline__ float softplus_f(float x) {
  return fmaxf(x, 0.f) + log1pf(__expf(-fabsf(x)));
}

extern "C" __global__ void vrnn_pack(const float* __restrict__ Wih, const float* __restrict__ Whh,
                                     const float* __restrict__ Wphi, const float* __restrict__ Wm,
                                     const float* __restrict__ Ws, ushort* __restrict__ o)
{
  int i = blockIdx.x * 256 + threadIdx.x;
  if (i >= N_PACK_THREADS) return;
  const float* src; int dst;
  if (i < 24576) {                    // Whh: 384 frags
    int f = i >> 6, l = i & 63;
    int tile = f >> 3, kb = f & 7;
    int n = tile * 16 + (l & 15), k0 = kb * 32 + 8 * (l >> 4);
    src = Whh + n * 256 + k0; dst = f * 512 + l * 8;
  } else if (i < 27648) {             // Wih: 48 frags (K=32, kb=0)
    int q = i - 24576, f = q >> 6, l = q & 63;
    int n = f * 16 + (l & 15), k0 = 8 * (l >> 4);
    src = Wih + n * 32 + k0; dst = OFF_WIH + f * 512 + l * 8;
  } else if (i < 35840) {             // Wphi: 128 frags
    int q = i - 27648, f = q >> 6, l = q & 63;
    int tile = f >> 3, kb = f & 7;
    int n = tile * 16 + (l & 15), k0 = kb * 32 + 8 * (l >> 4);
    src = Wphi + n * 256 + k0; dst = OFF_WPHI + f * 512 + l * 8;
  } else {                            // Wms: 64 frags (mean|std concat)
    int q = i - 35840, f = q >> 6, l = q & 63;
    int tile = f >> 3, kb = f & 7;
    int c = tile * 16 + (l & 15), k0 = kb * 32 + 8 * (l >> 4);
    src = (c < 64 ? Wm + c * 256 : Ws + (c - 64) * 256) + k0;
    dst = OFF_WMS + f * 512 + l * 8;
  }
  __align__(16) ushort tmp[8];
  #pragma unroll
  for (int j = 0; j < 8; ++j) tmp[j] = f2bf(src[j]);
  *reinterpret_cast<uint4*>(o + dst) = *reinterpret_cast<const uint4*>(tmp);
}

extern "C" __global__ void __launch_bounds__(512)
vrnn_mfma(const float* __restrict__ inp, const float* __restrict__ eps,
          const float* __restrict__ b_ih, const float* __restrict__ b_hh,
          const float* __restrict__ b_phi, const float* __restrict__ b_mean,
          const float* __restrict__ b_std,
          const ushort* __restrict__ wt, float* __restrict__ out)
{
  __shared__ ushort h_lds[2][16][264];   // stride 264: 2-way bank alias on b128 (free)
  __shared__ ushort phi_lds[16][264];
  __shared__ ushort x_lds[16][40];       // stride 40: 2-way alias (free)
  __shared__ float  ms_lds[2][16][64];   // [0]=mean [1]=std
  __shared__ float  bias[1408];          // bR|bZ|bIN|bHN|bPhi (256 each) | bMS(128)

  const int tid  = threadIdx.x;
  const int w    = tid >> 6;       // wave 0..7
  const int lane = tid & 63;
  const int ar   = lane & 15;      // A row / C col
  const int ag   = lane >> 4;      // A k-group / C row-group
  const int l8   = lane * 8;
  const int b0   = blockIdx.x * 16;

  const ushort* pWhh  = wt;
  const ushort* pWih  = wt + OFF_WIH;
  const ushort* pWphi = wt + OFF_WPHI;
  const ushort* pWms  = wt + OFF_WMS;

  if (tid < 256) {
    bias[tid]        = b_ih[tid] + b_hh[tid];            // r
    bias[256 + tid]  = b_ih[256 + tid] + b_hh[256 + tid];// z
    bias[512 + tid]  = b_ih[512 + tid];                  // i_n
    bias[768 + tid]  = b_hh[512 + tid];                  // h_n
    bias[1024 + tid] = b_phi[tid];
  } else if (tid < 384) {
    int c = tid - 256;
    bias[1280 + c] = (c < 64) ? b_mean[c] : b_std[c - 64];
  }
  for (int i = tid; i < 2 * 16 * 264; i += 512) ((ushort*)h_lds)[i] = 0;
  __syncthreads();

  const int tR0 = 2 * w, tZ0 = 16 + 2 * w, tN0 = 32 + 2 * w;  // col-tile bases
  const int colw = 32 * w + ar;                                // gate/phi col (u adds 16)
  int cur = 0;

  for (int step = 0; step < 256; ++step) {
    // ---- stage x_t (512 threads = 16 rows x 32 k) ----
    {
      int r = tid >> 5, k = tid & 31;
      x_lds[r][k] = f2bf(inp[((size_t)(b0 + r) * 256 + step) * 32 + k]);
    }
    __syncthreads();  // A: x ready (also fences prior-step ms_lds reads far upstream)

    // ---- gates: gi (K=32) + gh (K=256) ----
    f32x4 aR[2], aZ[2], aIN[2], aHN[2];
    #pragma unroll
    for (int u = 0; u < 2; ++u) {
      aR[u] = (f32x4){0.f, 0.f, 0.f, 0.f}; aZ[u] = aR[u]; aIN[u] = aR[u]; aHN[u] = aR[u];
    }
    {
      bf16x8 xa = LDFRAG(&x_lds[ar][ag * 8]);
      #pragma unroll
      for (int u = 0; u < 2; ++u) {
        aR[u]  = MFMA(xa, LDFRAG(pWih + (tR0 + u) * 512 + l8), aR[u]);
        aZ[u]  = MFMA(xa, LDFRAG(pWih + (tZ0 + u) * 512 + l8), aZ[u]);
        aIN[u] = MFMA(xa, LDFRAG(pWih + (tN0 + u) * 512 + l8), aIN[u]);
      }
    }
    #pragma unroll 2
    for (int kb = 0; kb < 8; ++kb) {
      bf16x8 ha = LDFRAG(&h_lds[cur][ar][kb * 32 + ag * 8]);
      #pragma unroll
      for (int u = 0; u < 2; ++u) {
        aR[u]  = MFMA(ha, LDFRAG(pWhh + ((tR0 + u) * 8 + kb) * 512 + l8), aR[u]);
        aZ[u]  = MFMA(ha, LDFRAG(pWhh + ((tZ0 + u) * 8 + kb) * 512 + l8), aZ[u]);
        aHN[u] = MFMA(ha, LDFRAG(pWhh + ((tN0 + u) * 8 + kb) * 512 + l8), aHN[u]);
      }
    }
    #pragma unroll
    for (int u = 0; u < 2; ++u) {
      int col = colw + 16 * u;
      float bR = bias[col], bZ = bias[256 + col], bIN = bias[512 + col], bHN = bias[768 + col];
      #pragma unroll
      for (int q = 0; q < 4; ++q) {
        int row = ag * 4 + q;
        float rg = sigm(aR[u][q] + bR);
        float zg = sigm(aZ[u][q] + bZ);
        float hp = bf2f(h_lds[cur][row][col]);
        float ng = tanh_f(aIN[u][q] + bIN + rg * (aHN[u][q] + bHN));
        h_lds[cur ^ 1][row][col] = f2bf((1.f - zg) * ng + zg * hp);
      }
    }
    __syncthreads();  // B: h_new ready

    // ---- phi = relu(h_new @ WphiT + b) ----
    f32x4 aP[2];
    #pragma unroll
    for (int u = 0; u < 2; ++u) aP[u] = (f32x4){0.f, 0.f, 0.f, 0.f};
    #pragma unroll 2
    for (int kb = 0; kb < 8; ++kb) {
      bf16x8 ha = LDFRAG(&h_lds[cur ^ 1][ar][kb * 32 + ag * 8]);
      #pragma unroll
      for (int u = 0; u < 2; ++u)
        aP[u] = MFMA(ha, LDFRAG(pWphi + ((2 * w + u) * 8 + kb) * 512 + l8), aP[u]);
    }
    #pragma unroll
    for (int u = 0; u < 2; ++u) {
      int col = colw + 16 * u;
      float bp = bias[1024 + col];
      #pragma unroll
      for (int q = 0; q < 4; ++q)
        phi_lds[ag * 4 + q][col] = f2bf(fmaxf(aP[u][q] + bp, 0.f));
    }
    __syncthreads();  // C: phi ready

    // ---- mean/std: waves 0-3 -> sigmoid(mean), waves 4-7 -> softplus(std) ----
    {
      f32x4 aM = (f32x4){0.f, 0.f, 0.f, 0.f};
      #pragma unroll 2
      for (int kb = 0; kb < 8; ++kb) {
        bf16x8 pa = LDFRAG(&phi_lds[ar][kb * 32 + ag * 8]);
        aM = MFMA(pa, LDFRAG(pWms + (w * 8 + kb) * 512 + l8), aM);
      }
      int c = 16 * (w & 3) + ar;
      int sel = w >> 2;
      float bm = bias[1280 + sel * 64 + c];
      #pragma unroll
      for (int q = 0; q < 4; ++q) {
        float v = aM[q] + bm;
        ms_lds[sel][ag * 4 + q][c] = sel ? softplus_f(v) : sigm(v);
      }
    }
    __syncthreads();  // D: mean/std ready

    // ---- epilogue: xs/mean/std to global ----
    #pragma unroll
    for (int part = 0; part < 2; ++part) {
      int idx = tid + part * 512;
      int row = idx >> 6, c = idx & 63;
      size_t o = ((size_t)(b0 + row) * 256 + step) * 64 + c;
      float mn = ms_lds[0][row][c], sd = ms_lds[1][row][c];
      out[o]                     = fmaf(eps[o], sd, mn);
      out[o + 16777216u]         = mn;
      out[o + 33554432u]         = sd;
    }
    cur ^= 1;
    // no barrier needed here: next ms_lds write is 3 barriers away
  }
}

extern "C" void kernel_launch(void* const* d_in, const int* in_sizes, int n_in,
                              void* d_out, int out_size, void* d_ws, size_t ws_size,
                              hipStream_t stream)
{
  const float* inp    = (const float*)d_in[0];
  const float* eps    = (const float*)d_in[1];
  const float* W_ih   = (const float*)d_in[2];
  const float* W_hh   = (const float*)d_in[3];
  const float* b_ih   = (const float*)d_in[4];
  const float* b_hh   = (const float*)d_in[5];
  const float* W_phi  = (const float*)d_in[6];
  const float* b_phi  = (const float*)d_in[7];
  const float* W_mean = (const float*)d_in[8];
  const float* b_mean = (const float*)d_in[9];
  const float* W_std  = (const float*)d_in[10];
  const float* b_std  = (const float*)d_in[11];
  ushort* wt = (ushort*)d_ws;   // 639KB packed bf16 fragments
  float* out = (float*)d_out;

  vrnn_pack<<<156, 256, 0, stream>>>(W_ih, W_hh, W_phi, W_mean, W_std, wt);
  vrnn_mfma<<<64, 512, 0, stream>>>(inp, eps, b_ih, b_hh, b_phi, b_mean, b_std, wt, out);
}

// Round 4
// 2245.398 us; speedup vs baseline: 3.9325x; 1.4899x over previous
//
#include <hip/hip_runtime.h>
#include <hip/hip_bf16.h>
#include <math.h>

// Decoder_60112362275053: VRNN decoder. B=1024 T=256 Z=32 H=256 D=256 X=64.
// Round 4: break the weights-from-L2 port wall (624 KB/step/CU @ ~64 B/cy
// ~= 9750 cy/step) by making the weight stream resident:
//   - Whh (384 KB) -> REGISTERS: 48 frags/wave = 192 VGPRs, loaded once.
//   - Wih (48 KB) + Wms (64 KB) -> LDS-resident (copied once).
//   - Wphi (128 KB/step) remains the only per-step L2 stream (~2000 cy).
//   - x_t in registers (per-wave A-frag, prefetched t+1); eps prefetched.
//   - biases folded into accumulator init; 3 barriers/step; 150.75 KB dyn LDS.
// Fragment conventions identical to the round-3 kernel (PASSED, absmax .0156):
//   A: lane l -> row=l&15, k=kb*32+8*(l>>4)+j ; B pre-packed with same k-map;
//   C/D: lane l, reg q -> col=l&15, row=(l>>4)*4+q  [HW-verified m89/m91]

typedef __attribute__((ext_vector_type(8))) short bf16x8;
typedef __attribute__((ext_vector_type(4))) float f32x4;

#define MFMA(a, b, c) __builtin_amdgcn_mfma_f32_16x16x32_bf16((a), (b), (c), 0, 0, 0)
#define LDFRAG(p) (*reinterpret_cast<const bf16x8*>(p))

// packed ws layout (ushort offsets), fragment = 512 ushorts (64 lanes x 8):
#define OFF_WIH  196608
#define OFF_WPHI 221184
#define OFF_WMS  286720
#define N_PACK_THREADS 39936

// dynamic LDS layout (byte offsets)
#define SM_WMS   0        // 65536 B  (32768 us)
#define SM_WIH   65536    // 49152 B  (24576 us)
#define SM_H     114688   // 16896 B  ([2][16][264] us)
#define SM_PHI   131584   // 8448 B   ([16][264] us)
#define SM_MS    140032   // 8704 B   ([2][16][68] f32)
#define SM_BIAS  148736   // 5632 B   (1408 f32)
#define SMEM_BYTES 154368

__device__ __forceinline__ float bf2f(ushort u) {
  union { unsigned int i; float f; } v; v.i = ((unsigned int)u) << 16; return v.f;
}
__device__ __forceinline__ ushort f2bf(float f) {
  union { __hip_bfloat16 h; ushort u; } cv; cv.h = __float2bfloat16(f); return cv.u;
}
__device__ __forceinline__ float sigm(float x) { return 1.f / (1.f + __expf(-x)); }
__device__ __forceinline__ float tanh_f(float x) { return 2.f / (1.f + __expf(-2.f * x)) - 1.f; }
__device__ __forceinline__ float softplus_f(float x) {
  return fmaxf(x, 0.f) + log1pf(__expf(-fabsf(x)));
}

extern "C" __global__ void vrnn_pack(const float* __restrict__ Wih, const float* __restrict__ Whh,
                                     const float* __restrict__ Wphi, const float* __restrict__ Wm,
                                     const float* __restrict__ Ws, ushort* __restrict__ o)
{
  int i = blockIdx.x * 256 + threadIdx.x;
  if (i >= N_PACK_THREADS) return;
  const float* src; int dst;
  if (i < 24576) {                    // Whh: 384 frags (tiles: R 0-15, Z 16-31, N 32-47)
    int f = i >> 6, l = i & 63;
    int tile = f >> 3, kb = f & 7;
    int n = tile * 16 + (l & 15), k0 = kb * 32 + 8 * (l >> 4);
    src = Whh + n * 256 + k0; dst = f * 512 + l * 8;
  } else if (i < 27648) {             // Wih: 48 frags (K=32)
    int q = i - 24576, f = q >> 6, l = q & 63;
    int n = f * 16 + (l & 15), k0 = 8 * (l >> 4);
    src = Wih + n * 32 + k0; dst = OFF_WIH + f * 512 + l * 8;
  } else if (i < 35840) {             // Wphi: 128 frags
    int q = i - 27648, f = q >> 6, l = q & 63;
    int tile = f >> 3, kb = f & 7;
    int n = tile * 16 + (l & 15), k0 = kb * 32 + 8 * (l >> 4);
    src = Wphi + n * 256 + k0; dst = OFF_WPHI + f * 512 + l * 8;
  } else {                            // Wms: 64 frags (cols 0-63 mean | 64-127 std)
    int q = i - 35840, f = q >> 6, l = q & 63;
    int tile = f >> 3, kb = f & 7;
    int c = tile * 16 + (l & 15), k0 = kb * 32 + 8 * (l >> 4);
    src = (c < 64 ? Wm + c * 256 : Ws + (c - 64) * 256) + k0;
    dst = OFF_WMS + f * 512 + l * 8;
  }
  __align__(16) ushort tmp[8];
  #pragma unroll
  for (int j = 0; j < 8; ++j) tmp[j] = f2bf(src[j]);
  *reinterpret_cast<uint4*>(o + dst) = *reinterpret_cast<const uint4*>(tmp);
}

extern "C" __global__ void __launch_bounds__(512, 2)
vrnn_mfma2(const float* __restrict__ inp, const float* __restrict__ eps,
           const float* __restrict__ b_ih, const float* __restrict__ b_hh,
           const float* __restrict__ b_phi, const float* __restrict__ b_mean,
           const float* __restrict__ b_std,
           const ushort* __restrict__ wt, float* __restrict__ out)
{
  extern __shared__ char smem[];
  ushort* wms_s = (ushort*)(smem + SM_WMS);
  ushort* wih_s = (ushort*)(smem + SM_WIH);
  ushort* h_s   = (ushort*)(smem + SM_H);    // [2][16][264]
  ushort* phi_s = (ushort*)(smem + SM_PHI);  // [16][264]
  float*  ms_s  = (float*)(smem + SM_MS);    // [2][16][68]
  float*  bias  = (float*)(smem + SM_BIAS);  // [1408]

  const int tid  = threadIdx.x;
  const int w    = tid >> 6;
  const int lane = tid & 63;
  const int ar   = lane & 15;
  const int ag   = lane >> 4;
  const int l8   = lane * 8;
  const int b0   = blockIdx.x * 16;

  const ushort* pWhh  = wt;
  const ushort* pWphi = wt + OFF_WPHI;

  // ---- one-time: stage Wms + Wih into LDS (packed layout is linear) ----
  {
    const uint4* s0 = (const uint4*)(wt + OFF_WMS);
    uint4* d0 = (uint4*)wms_s;
    for (int i = tid; i < 4096; i += 512) d0[i] = s0[i];
    const uint4* s1 = (const uint4*)(wt + OFF_WIH);
    uint4* d1 = (uint4*)wih_s;
    for (int i = tid; i < 3072; i += 512) d1[i] = s1[i];
  }
  // ---- biases ----
  if (tid < 256) {
    bias[tid]        = b_ih[tid]       + b_hh[tid];
    bias[256 + tid]  = b_ih[256 + tid] + b_hh[256 + tid];
    bias[512 + tid]  = b_ih[512 + tid];
    bias[768 + tid]  = b_hh[512 + tid];
    bias[1024 + tid] = b_phi[tid];
  } else if (tid < 384) {
    int c = tid - 256;
    bias[1280 + c] = (c < 64) ? b_mean[c] : b_std[c - 64];
  }
  // ---- zero h buffer 0 ----
  for (int i = tid; i < 16 * 264; i += 512) h_s[i] = 0;

  // ---- Whh into registers: whh[u][g][kb], 192 VGPRs, static-indexed ----
  bf16x8 whh[2][3][8];
  #pragma unroll
  for (int u = 0; u < 2; ++u)
    #pragma unroll
    for (int g = 0; g < 3; ++g)
      #pragma unroll
      for (int kb = 0; kb < 8; ++kb)
        whh[u][g][kb] = LDFRAG(pWhh + (size_t)((g * 16 + 2 * w + u) * 8 + kb) * 512 + l8);

  // ---- x[0] into registers (per-wave A-frag source) ----
  float xf[8];
  {
    const float* xp = inp + ((size_t)(b0 + ar) * 256 + 0) * 32 + ag * 8;
    #pragma unroll
    for (int j = 0; j < 8; ++j) xf[j] = xp[j];
  }
  __syncthreads();

  const int colbase = 32 * w + ar;
  const size_t ob0 = ((size_t)(b0 + w) * 256) * 64 + lane;
  const size_t ob1 = ((size_t)(b0 + w + 8) * 256) * 64 + lane;

  int cur = 0;
  for (int t = 0; t < 256; ++t) {
    const int nxt = cur ^ 1;
    // x_t fragment (bf16)
    bf16x8 xa;
    #pragma unroll
    for (int j = 0; j < 8; ++j) xa[j] = (short)f2bf(xf[j]);

    // ---- gates, u-sequential ----
    #pragma unroll
    for (int u = 0; u < 2; ++u) {
      const int col = colbase + 16 * u;
      const float bR = bias[col], bZ = bias[256 + col];
      const float bIN = bias[512 + col], bHN = bias[768 + col];
      f32x4 aR  = {bR, bR, bR, bR};
      f32x4 aZ  = {bZ, bZ, bZ, bZ};
      f32x4 aIN = {bIN, bIN, bIN, bIN};
      f32x4 aHN = {bHN, bHN, bHN, bHN};
      #pragma unroll
      for (int kb = 0; kb < 8; ++kb) {
        bf16x8 ha = LDFRAG(h_s + cur * 4224 + ar * 264 + kb * 32 + ag * 8);
        aR  = MFMA(ha, whh[u][0][kb], aR);
        aZ  = MFMA(ha, whh[u][1][kb], aZ);
        aHN = MFMA(ha, whh[u][2][kb], aHN);
      }
      aR  = MFMA(xa, LDFRAG(wih_s + (      2 * w + u) * 512 + l8), aR);
      aZ  = MFMA(xa, LDFRAG(wih_s + (16 + 2 * w + u) * 512 + l8), aZ);
      aIN = MFMA(xa, LDFRAG(wih_s + (32 + 2 * w + u) * 512 + l8), aIN);
      #pragma unroll
      for (int q = 0; q < 4; ++q) {
        const int row = ag * 4 + q;
        float rg = sigm(aR[q]);
        float zg = sigm(aZ[q]);
        float hp = bf2f(h_s[cur * 4224 + row * 264 + col]);
        float ng = tanh_f(aIN[q] + rg * aHN[q]);
        h_s[nxt * 4224 + row * 264 + col] = f2bf((1.f - zg) * ng + zg * hp);
      }
    }

    // ---- prefetch Wphi u=0 frags (only per-step L2 weight stream) ----
    bf16x8 wp[8];
    #pragma unroll
    for (int kb = 0; kb < 8; ++kb)
      wp[kb] = LDFRAG(pWphi + (size_t)((2 * w) * 8 + kb) * 512 + l8);

    __syncthreads();  // bar1: h_new ready

    // prefetch eps + x[t+1] (consumed 2 phases later)
    const size_t o0 = ob0 + (size_t)t * 64;
    const size_t o1 = ob1 + (size_t)t * 64;
    float e0 = eps[o0], e1 = eps[o1];
    {
      const int tn = (t < 255) ? t + 1 : 255;
      const float* xp = inp + ((size_t)(b0 + ar) * 256 + tn) * 32 + ag * 8;
      #pragma unroll
      for (int j = 0; j < 8; ++j) xf[j] = xp[j];
    }

    // ---- phi u=0 ----
    {
      const float bp = bias[1024 + colbase];
      f32x4 aP = {bp, bp, bp, bp};
      #pragma unroll
      for (int kb = 0; kb < 8; ++kb) {
        bf16x8 ha = LDFRAG(h_s + nxt * 4224 + ar * 264 + kb * 32 + ag * 8);
        aP = MFMA(ha, wp[kb], aP);
      }
      #pragma unroll
      for (int q = 0; q < 4; ++q)
        phi_s[(ag * 4 + q) * 264 + colbase] = f2bf(fmaxf(aP[q], 0.f));
    }
    // ---- phi u=1 (reload wp) ----
    #pragma unroll
    for (int kb = 0; kb < 8; ++kb)
      wp[kb] = LDFRAG(pWphi + (size_t)((2 * w + 1) * 8 + kb) * 512 + l8);
    {
      const int col = colbase + 16;
      const float bp = bias[1024 + col];
      f32x4 aP = {bp, bp, bp, bp};
      #pragma unroll
      for (int kb = 0; kb < 8; ++kb) {
        bf16x8 ha = LDFRAG(h_s + nxt * 4224 + ar * 264 + kb * 32 + ag * 8);
        aP = MFMA(ha, wp[kb], aP);
      }
      #pragma unroll
      for (int q = 0; q < 4; ++q)
        phi_s[(ag * 4 + q) * 264 + col] = f2bf(fmaxf(aP[q], 0.f));
    }
    __syncthreads();  // bar2: phi ready

    // ---- mean/std: waves 0-3 sigmoid(mean), 4-7 softplus(std) ----
    {
      const int cms = 16 * (w & 3) + ar;
      const int sel = w >> 2;
      const float bm = bias[1280 + sel * 64 + cms];
      f32x4 aM = {bm, bm, bm, bm};
      #pragma unroll
      for (int kb = 0; kb < 8; ++kb) {
        bf16x8 pa = LDFRAG(phi_s + ar * 264 + kb * 32 + ag * 8);
        aM = MFMA(pa, LDFRAG(wms_s + (w * 8 + kb) * 512 + l8), aM);
      }
      #pragma unroll
      for (int q = 0; q < 4; ++q) {
        float v = aM[q];
        ms_s[sel * 1088 + (ag * 4 + q) * 68 + cms] = sel ? softplus_f(v) : sigm(v);
      }
    }
    __syncthreads();  // bar3: mean/std ready

    // ---- out: rows w and w+8, col = lane ----
    {
      float m0 = ms_s[w * 68 + lane],        s0 = ms_s[1088 + w * 68 + lane];
      float m1 = ms_s[(w + 8) * 68 + lane],  s1 = ms_s[1088 + (w + 8) * 68 + lane];
      out[o0]            = fmaf(e0, s0, m0);
      out[o0 + 16777216] = m0;
      out[o0 + 33554432] = s0;
      out[o1]            = fmaf(e1, s1, m1);
      out[o1 + 16777216] = m1;
      out[o1 + 33554432] = s1;
    }
    // no 4th barrier: next ms_s/phi_s writes are >=2 barriers downstream
    cur ^= 1;
  }
}

extern "C" void kernel_launch(void* const* d_in, const int* in_sizes, int n_in,
                              void* d_out, int out_size, void* d_ws, size_t ws_size,
                              hipStream_t stream)
{
  const float* inp    = (const float*)d_in[0];
  const float* eps    = (const float*)d_in[1];
  const float* W_ih   = (const float*)d_in[2];
  const float* W_hh   = (const float*)d_in[3];
  const float* b_ih   = (const float*)d_in[4];
  const float* b_hh   = (const float*)d_in[5];
  const float* W_phi  = (const float*)d_in[6];
  const float* b_phi  = (const float*)d_in[7];
  const float* W_mean = (const float*)d_in[8];
  const float* b_mean = (const float*)d_in[9];
  const float* W_std  = (const float*)d_in[10];
  const float* b_std  = (const float*)d_in[11];
  ushort* wt = (ushort*)d_ws;   // 639KB packed bf16 fragments
  float* out = (float*)d_out;

  hipFuncSetAttribute((const void*)vrnn_mfma2,
                      hipFuncAttributeMaxDynamicSharedMemorySize, SMEM_BYTES);
  vrnn_pack<<<156, 256, 0, stream>>>(W_ih, W_hh, W_phi, W_mean, W_std, wt);
  vrnn_mfma2<<<64, 512, SMEM_BYTES, stream>>>(inp, eps, b_ih, b_hh, b_phi,
                                              b_mean, b_std, wt, out);
}